// Round 3
// baseline (512.530 us; speedup 1.0000x reference)
//
#include <hip/hip_runtime.h>

#define Bc 8
#define Tc 4096
#define Dc 768
#define Hc 12
#define HDc 64
#define Kc 32
#define TD3 2304

typedef __attribute__((ext_vector_type(8))) short short8;
typedef __attribute__((ext_vector_type(4))) float float4v;
typedef __attribute__((ext_vector_type(2))) float float2v;

__device__ __forceinline__ float bf2f(unsigned short u) {
    unsigned v = ((unsigned)u) << 16;
    return __builtin_bit_cast(float, v);
}
__device__ __forceinline__ unsigned short f2bf(float f) {
    unsigned u = __builtin_bit_cast(unsigned, f);
    u += 0x7FFFu + ((u >> 16) & 1u);   // RNE
    return (unsigned short)(u >> 16);
}

// split fp32x8 into bf16 hi + bf16 lo fragments (hi+lo ~ fp32 precision)
__device__ __forceinline__ void split8(const float* p, short8& hi, short8& lo) {
    float4v a0 = *(const float4v*)p;
    float4v a1 = *(const float4v*)(p + 4);
#pragma unroll
    for (int i = 0; i < 4; ++i) {
        unsigned short h = f2bf(a0[i]);
        hi[i] = (short)h;
        lo[i] = (short)f2bf(a0[i] - bf2f(h));
        unsigned short h2 = f2bf(a1[i]);
        hi[i + 4] = (short)h2;
        lo[i + 4] = (short)f2bf(a1[i] - bf2f(h2));
    }
}
__device__ __forceinline__ void split8v(float4v a0, float4v a1, short8& hi, short8& lo) {
#pragma unroll
    for (int i = 0; i < 4; ++i) {
        unsigned short h = f2bf(a0[i]);
        hi[i] = (short)h;
        lo[i] = (short)f2bf(a0[i] - bf2f(h));
        unsigned short h2 = f2bf(a1[i]);
        hi[i + 4] = (short)h2;
        lo[i + 4] = (short)f2bf(a1[i] - bf2f(h2));
    }
}

// K1: x_spec[b,k,d] = sum_t sb[b,t,k] * x[b,t,d]  (atomic over 32 T-chunks of 128)
// sb rows are wave-uniform -> scalar loads (no LDS). x via dwordx2 + depth-8 prefetch ring.
__global__ __launch_bounds__(384) void k1_xspec(const float* __restrict__ x,
                                                const float* __restrict__ sb,
                                                float* __restrict__ xs) {
    int tid = threadIdx.x;              // 0..383, owns columns d, d+1
    int b   = blockIdx.x >> 5;          // grid = 8*32 = 256 blocks
    int tc  = blockIdx.x & 31;
    int t0  = tc * 128;
    int d   = tid * 2;

    const float* xp  = x  + ((size_t)(b * Tc + t0)) * Dc + d;
    const float* sbp = sb + ((size_t)(b * Tc + t0)) * Kc;

    float2v acc[Kc];
#pragma unroll
    for (int k = 0; k < Kc; ++k) acc[k] = (float2v){0.f, 0.f};

    float2v xbuf[8];
#pragma unroll
    for (int p = 0; p < 8; ++p) xbuf[p] = *(const float2v*)(xp + (size_t)p * Dc);

#pragma unroll 8
    for (int tt = 0; tt < 128; ++tt) {
        float2v xv = xbuf[tt & 7];
        if (tt + 8 < 128) xbuf[tt & 7] = *(const float2v*)(xp + (size_t)(tt + 8) * Dc);
        const float* srow = sbp + tt * Kc;   // uniform address -> s_load
        float4v s4[8];
#pragma unroll
        for (int j = 0; j < 8; ++j) s4[j] = *(const float4v*)(srow + j * 4);
#pragma unroll
        for (int k = 0; k < Kc; ++k) {
            float s = s4[k >> 2][k & 3];
            acc[k][0] = fmaf(s, xv[0], acc[k][0]);
            acc[k][1] = fmaf(s, xv[1], acc[k][1]);
        }
    }

    float* xsp = xs + (size_t)b * Kc * Dc + d;
#pragma unroll
    for (int k = 0; k < Kc; ++k) {
        atomicAdd(xsp + (size_t)k * Dc,     acc[k][0]);
        atomicAdd(xsp + (size_t)k * Dc + 1, acc[k][1]);
    }
}

// K2: c1[r, j] = sum_c xs[r, c] * wqkv[j, c];  (validated round-2 version, unchanged)
__global__ __launch_bounds__(256) void k2_qkv(const float* __restrict__ xs,
                                              const float* __restrict__ wqkv,
                                              float* __restrict__ c1) {
    int wave = blockIdx.x * 4 + (threadIdx.x >> 6);   // 72 blocks -> 288 waves
    int lane = threadIdx.x & 63;
    int mb = wave & 3;
    int nt = wave >> 2;
    int m0 = mb * 64, n0 = nt * 32;
    int m = lane & 15, quad = lane >> 4;

    const float* ap  = xs   + (size_t)(m0 + m) * Dc + quad * 8;
    const float* bp0 = wqkv + (size_t)(n0 + m) * Dc + quad * 8;
    const float* bp1 = bp0 + (size_t)16 * Dc;

    float4v acc[4][2];
#pragma unroll
    for (int i = 0; i < 4; ++i)
#pragma unroll
        for (int j = 0; j < 2; ++j) acc[i][j] = (float4v){0.f, 0.f, 0.f, 0.f};

    for (int s = 0; s < 24; ++s) {
        short8 bh0, bl0, bh1, bl1;
        split8(bp0 + s * 32, bh0, bl0);
        split8(bp1 + s * 32, bh1, bl1);
#pragma unroll
        for (int mt = 0; mt < 4; ++mt) {
            short8 ah, al;
            split8(ap + (size_t)mt * 16 * Dc + s * 32, ah, al);
            acc[mt][0] = __builtin_amdgcn_mfma_f32_16x16x32_bf16(ah, bh0, acc[mt][0], 0, 0, 0);
            acc[mt][0] = __builtin_amdgcn_mfma_f32_16x16x32_bf16(al, bh0, acc[mt][0], 0, 0, 0);
            acc[mt][0] = __builtin_amdgcn_mfma_f32_16x16x32_bf16(ah, bl0, acc[mt][0], 0, 0, 0);
            acc[mt][1] = __builtin_amdgcn_mfma_f32_16x16x32_bf16(ah, bh1, acc[mt][1], 0, 0, 0);
            acc[mt][1] = __builtin_amdgcn_mfma_f32_16x16x32_bf16(al, bh1, acc[mt][1], 0, 0, 0);
            acc[mt][1] = __builtin_amdgcn_mfma_f32_16x16x32_bf16(ah, bl1, acc[mt][1], 0, 0, 0);
        }
    }
    int col = lane & 15;
#pragma unroll
    for (int mt = 0; mt < 4; ++mt) {
        float* cp = c1 + (size_t)(m0 + mt * 16 + quad * 4) * TD3 + n0 + col;
#pragma unroll
        for (int r = 0; r < 4; ++r) {
            cp[(size_t)r * TD3]      = acc[mt][0][r];
            cp[(size_t)r * TD3 + 16] = acc[mt][1][r];
        }
    }
}

// K3: attn dot (q.k)/8 * sigmoid(filter) -> FHN (validated, unchanged)
__global__ __launch_bounds__(256) void k3_fhn(const float* __restrict__ c1,
                                              const float* __restrict__ sfilt,
                                              float* __restrict__ fhn) {
    int idx = blockIdx.x * 256 + threadIdx.x;
    if (idx >= Bc * Hc * Kc) return;
    int kk = idx & 31;
    int bh = idx >> 5;
    int h  = bh % Hc;
    int r  = (bh / Hc) * Kc + kk;

    const float* qp = c1 + (size_t)r * TD3 + h * HDc;
    const float* kp = qp + Dc;
    float s = 0.f;
#pragma unroll
    for (int dd = 0; dd < HDc; ++dd) s = fmaf(qp[dd], kp[dd], s);
    s *= 0.125f;

    float filt = 1.f / (1.f + __expf(-sfilt[h * 32 + kk]));
    s *= filt;

    float as    = fabsf(s);
    float scale = fmaxf(as, 1e-6f);
    float sn    = s / scale;
    float gate  = 1.f / (1.f + __expf(-(as - 0.5f) * 10.f));
    float I     = sn * (0.1f + 0.9f * gate);
    const float alpha = 0.08f;
    const float denom = 1.064f;
    float v = 0.f, w = 0.f;
#pragma unroll
    for (int it = 0; it < 2; ++it) {
        float dv = v - (v * v * v) / 3.f - w + I;
        float vn = v + dv;
        float wn = (w + (vn + 0.7f) * alpha) / denom;
        v = fminf(fmaxf(vn, -3.f), 3.f);
        w = fminf(fmaxf(wn, -3.f), 3.f);
    }
    fhn[idx] = v * scale;
}

// K4: proj[r,e] = sum_c (fhn * v_spec[r,c]) * wout[e,c] (validated, unchanged)
__global__ __launch_bounds__(256) void k4_proj(const float* __restrict__ c1,
                                               const float* __restrict__ fhn,
                                               const float* __restrict__ wout,
                                               float* __restrict__ proj) {
    int wave = blockIdx.x * 4 + (threadIdx.x >> 6);   // 48 blocks -> 192 waves
    int lane = threadIdx.x & 63;
    int mb = wave & 3;
    int nt = wave >> 2;
    int m0 = mb * 64, n0 = nt * 16;
    int m = lane & 15, quad = lane >> 4;

    const float* bp = wout + (size_t)(n0 + m) * Dc + quad * 8;

    float4v acc[4];
#pragma unroll
    for (int i = 0; i < 4; ++i) acc[i] = (float4v){0.f, 0.f, 0.f, 0.f};

    for (int s = 0; s < 24; ++s) {
        short8 bh, bl;
        split8(bp + s * 32, bh, bl);
        int c0 = s * 32 + quad * 8;
        int h  = c0 >> 6;
#pragma unroll
        for (int mt = 0; mt < 4; ++mt) {
            int r = m0 + mt * 16 + m;
            int b = r >> 5, kk = r & 31;
            float f = fhn[(size_t)b * Hc * Kc + h * Kc + kk];
            const float* apx = c1 + (size_t)r * TD3 + 2 * Dc + s * 32 + quad * 8;
            float4v a0 = *(const float4v*)apx;
            float4v a1 = *(const float4v*)(apx + 4);
#pragma unroll
            for (int i = 0; i < 4; ++i) { a0[i] *= f; a1[i] *= f; }
            short8 ah, al;
            split8v(a0, a1, ah, al);
            acc[mt] = __builtin_amdgcn_mfma_f32_16x16x32_bf16(ah, bh, acc[mt], 0, 0, 0);
            acc[mt] = __builtin_amdgcn_mfma_f32_16x16x32_bf16(al, bh, acc[mt], 0, 0, 0);
            acc[mt] = __builtin_amdgcn_mfma_f32_16x16x32_bf16(ah, bl, acc[mt], 0, 0, 0);
        }
    }
#pragma unroll
    for (int mt = 0; mt < 4; ++mt) {
        float* cp = proj + (size_t)(m0 + mt * 16 + quad * 4) * Dc + n0 + (lane & 15);
#pragma unroll
        for (int r = 0; r < 4; ++r) cp[(size_t)r * Dc] = acc[mt][r];
    }
}

// K5: out[b,t,e] = sum_k sb[b,t,k] * proj[b,k,e]
// proj row-block in registers (float2/thread), sb via scalar loads, dwordx2 stores.
__global__ __launch_bounds__(384) void k5_out(const float* __restrict__ proj,
                                              const float* __restrict__ sb,
                                              float* __restrict__ out) {
    int tid = threadIdx.x;              // 0..383, owns columns d, d+1
    int b   = blockIdx.x >> 5;          // grid = 8*32 = 256 blocks
    int tc  = blockIdx.x & 31;
    int t0  = tc * 128;
    int d   = tid * 2;

    float2v p[Kc];
    const float* pp = proj + (size_t)b * Kc * Dc + d;
#pragma unroll
    for (int k = 0; k < Kc; ++k) p[k] = *(const float2v*)(pp + (size_t)k * Dc);

    const float* sbp = sb + ((size_t)(b * Tc + t0)) * Kc;
    float* op = out + ((size_t)(b * Tc + t0)) * Dc + d;

#pragma unroll 4
    for (int tt = 0; tt < 128; ++tt) {
        const float* srow = sbp + tt * Kc;   // uniform address -> s_load
        float4v s4[8];
#pragma unroll
        for (int j = 0; j < 8; ++j) s4[j] = *(const float4v*)(srow + j * 4);
        float a0 = 0.f, a1 = 0.f;
#pragma unroll
        for (int k = 0; k < Kc; ++k) {
            float s = s4[k >> 2][k & 3];
            a0 = fmaf(s, p[k][0], a0);
            a1 = fmaf(s, p[k][1], a1);
        }
        float2v a = {a0, a1};
        *(float2v*)(op + (size_t)tt * Dc) = a;
    }
}

extern "C" void kernel_launch(void* const* d_in, const int* in_sizes, int n_in,
                              void* d_out, int out_size, void* d_ws, size_t ws_size,
                              hipStream_t stream) {
    const float* x     = (const float*)d_in[0];
    const float* sb    = (const float*)d_in[1];
    const float* wqkv  = (const float*)d_in[2];
    const float* wout  = (const float*)d_in[3];
    const float* sfilt = (const float*)d_in[4];
    float* out = (float*)d_out;

    float* xs   = (float*)d_ws;                 // [B][K][D]   196608 f
    float* c1   = xs + (size_t)Bc * Kc * Dc;    // [256][2304] 589824 f
    float* fhn  = c1 + (size_t)Bc * Kc * TD3;   // [B][H][K]     3072 f
    float* proj = fhn + (size_t)Bc * Hc * Kc;   // [256][768]  196608 f

    hipMemsetAsync(xs, 0, (size_t)Bc * Kc * Dc * sizeof(float), stream);
    hipLaunchKernelGGL(k1_xspec, dim3(256), dim3(384), 0, stream, x, sb, xs);
    hipLaunchKernelGGL(k2_qkv,   dim3(72),  dim3(256), 0, stream, xs, wqkv, c1);
    hipLaunchKernelGGL(k3_fhn,   dim3(12),  dim3(256), 0, stream, c1, sfilt, fhn);
    hipLaunchKernelGGL(k4_proj,  dim3(48),  dim3(256), 0, stream, c1, fhn, wout, proj);
    hipLaunchKernelGGL(k5_out,   dim3(256), dim3(384), 0, stream, proj, sb, out);
}

// Round 4
// 405.508 us; speedup vs baseline: 1.2639x; 1.2639x over previous
//
#include <hip/hip_runtime.h>

#define Bc 8
#define Tc 4096
#define Dc 768
#define Hc 12
#define HDc 64
#define Kc 32
#define TD3 2304

typedef __attribute__((ext_vector_type(8))) short short8;
typedef __attribute__((ext_vector_type(4))) float float4v;

__device__ __forceinline__ float bf2f(unsigned short u) {
    unsigned v = ((unsigned)u) << 16;
    return __builtin_bit_cast(float, v);
}
__device__ __forceinline__ unsigned short f2bf(float f) {
    unsigned u = __builtin_bit_cast(unsigned, f);
    u += 0x7FFFu + ((u >> 16) & 1u);   // RNE
    return (unsigned short)(u >> 16);
}

// split 8 fp32 into bf16 hi + bf16 lo fragments (hi+lo ~ fp32 precision)
__device__ __forceinline__ void split8(const float* p, short8& hi, short8& lo) {
#pragma unroll
    for (int i = 0; i < 8; ++i) {
        unsigned short h = f2bf(p[i]);
        hi[i] = (short)h;
        lo[i] = (short)f2bf(p[i] - bf2f(h));
    }
}

// ---------------------------------------------------------------------------
// K1: pb[tc][b][kk][d] = sum_{t in chunk tc} sb[b,t,kk] * x[b,t,d]
// MFMA GEMM: M=32 (kk), N=768 (d), K=4096 (t). Verified k2 fragment idiom:
//   A: lane&15 -> output row (kk), quad*8+j -> k (t)
//   B: lane&15 -> output col (d),  quad*8+j -> k (t)
//   C: row = quad*4+r, col = lane&15
// Grid 256 = 8b x 4dt(192 d) x 8tc(512 t); block 512 thr = 8 waves splitting t.
// Cross-wave reduce via LDS ds_add_f32; exclusive pb write (no global atomics).
// ---------------------------------------------------------------------------
__global__ __launch_bounds__(512) void k1_xspec(const float* __restrict__ x,
                                                const float* __restrict__ sb,
                                                float* __restrict__ pb) {
    __shared__ float lacc[32 * 192];   // 24 KB

    int tid  = threadIdx.x;
    int w    = tid >> 6;
    int lane = tid & 63;
    int col  = lane & 15;
    int quad = lane >> 4;

    int bid = blockIdx.x;
    int b  = bid >> 5;
    int dt = (bid >> 3) & 3;
    int tc = bid & 7;
    int d0 = dt * 192;
    int t0 = tc * 512 + w * 64;
    size_t bT = (size_t)b * Tc;

    // zero LDS accumulator
    for (int i = tid; i < 32 * 192; i += 512) lacc[i] = 0.f;
    __syncthreads();

    float4v acc[2][12];
#pragma unroll
    for (int mi = 0; mi < 2; ++mi)
#pragma unroll
        for (int ni = 0; ni < 12; ++ni) acc[mi][ni] = (float4v){0.f, 0.f, 0.f, 0.f};

    for (int ks = 0; ks < 2; ++ks) {
        int tbase = t0 + ks * 32;
        // A fragments: sb[t, kk], two m-tiles
        short8 ah[2], al[2];
#pragma unroll
        for (int mi = 0; mi < 2; ++mi) {
            float av[8];
#pragma unroll
            for (int j = 0; j < 8; ++j)
                av[j] = sb[(bT + tbase + quad * 8 + j) * Kc + mi * 16 + col];
            split8(av, ah[mi], al[mi]);
        }
        // B fragments: x[t, d], 12 n-subtiles
#pragma unroll
        for (int ni = 0; ni < 12; ++ni) {
            float bv[8];
#pragma unroll
            for (int j = 0; j < 8; ++j)
                bv[j] = x[(bT + tbase + quad * 8 + j) * Dc + d0 + ni * 16 + col];
            short8 bh, bl;
            split8(bv, bh, bl);
#pragma unroll
            for (int mi = 0; mi < 2; ++mi) {
                acc[mi][ni] = __builtin_amdgcn_mfma_f32_16x16x32_bf16(ah[mi], bh, acc[mi][ni], 0, 0, 0);
                acc[mi][ni] = __builtin_amdgcn_mfma_f32_16x16x32_bf16(al[mi], bh, acc[mi][ni], 0, 0, 0);
                acc[mi][ni] = __builtin_amdgcn_mfma_f32_16x16x32_bf16(ah[mi], bl, acc[mi][ni], 0, 0, 0);
            }
        }
    }

    // cross-wave accumulate in LDS
#pragma unroll
    for (int mi = 0; mi < 2; ++mi)
#pragma unroll
        for (int ni = 0; ni < 12; ++ni)
#pragma unroll
            for (int r = 0; r < 4; ++r) {
                int kk = mi * 16 + quad * 4 + r;
                int dd = ni * 16 + col;
                atomicAdd(&lacc[kk * 192 + dd], acc[mi][ni][r]);
            }
    __syncthreads();

    // write exclusive partial: pb[tc][b][kk][d0..d0+192)
    float* pbp = pb + (size_t)tc * (Bc * Kc * Dc);
    for (int i = tid; i < (32 * 192) / 4; i += 512) {
        int row = i / 48;
        int c4  = i % 48;
        float4v v = *(const float4v*)&lacc[row * 192 + c4 * 4];
        *(float4v*)(pbp + ((size_t)(b * Kc + row)) * Dc + d0 + c4 * 4) = v;
    }
}

// reduce 8 partials -> xs
__global__ __launch_bounds__(256) void k1r_reduce(const float* __restrict__ pb,
                                                  float* __restrict__ xs) {
    int i = (blockIdx.x * 256 + threadIdx.x) * 4;   // 192 blocks -> 196608 floats
    float4v s = (float4v){0.f, 0.f, 0.f, 0.f};
#pragma unroll
    for (int p = 0; p < 8; ++p) {
        float4v v = *(const float4v*)(pb + (size_t)p * (Bc * Kc * Dc) + i);
#pragma unroll
        for (int q = 0; q < 4; ++q) s[q] += v[q];
    }
    *(float4v*)(xs + i) = s;
}

// K2: c1[r, j] = sum_c xs[r, c] * wqkv[j, c]  (validated, unchanged)
__global__ __launch_bounds__(256) void k2_qkv(const float* __restrict__ xs,
                                              const float* __restrict__ wqkv,
                                              float* __restrict__ c1) {
    int wave = blockIdx.x * 4 + (threadIdx.x >> 6);   // 72 blocks -> 288 waves
    int lane = threadIdx.x & 63;
    int mb = wave & 3;
    int nt = wave >> 2;
    int m0 = mb * 64, n0 = nt * 32;
    int m = lane & 15, quad = lane >> 4;

    const float* ap  = xs   + (size_t)(m0 + m) * Dc + quad * 8;
    const float* bp0 = wqkv + (size_t)(n0 + m) * Dc + quad * 8;
    const float* bp1 = bp0 + (size_t)16 * Dc;

    float4v acc[4][2];
#pragma unroll
    for (int i = 0; i < 4; ++i)
#pragma unroll
        for (int j = 0; j < 2; ++j) acc[i][j] = (float4v){0.f, 0.f, 0.f, 0.f};

    for (int s = 0; s < 24; ++s) {
        short8 bh0, bl0, bh1, bl1;
        split8(bp0 + s * 32, bh0, bl0);
        split8(bp1 + s * 32, bh1, bl1);
#pragma unroll
        for (int mt = 0; mt < 4; ++mt) {
            short8 ah, al;
            split8(ap + (size_t)mt * 16 * Dc + s * 32, ah, al);
            acc[mt][0] = __builtin_amdgcn_mfma_f32_16x16x32_bf16(ah, bh0, acc[mt][0], 0, 0, 0);
            acc[mt][0] = __builtin_amdgcn_mfma_f32_16x16x32_bf16(al, bh0, acc[mt][0], 0, 0, 0);
            acc[mt][0] = __builtin_amdgcn_mfma_f32_16x16x32_bf16(ah, bl0, acc[mt][0], 0, 0, 0);
            acc[mt][1] = __builtin_amdgcn_mfma_f32_16x16x32_bf16(ah, bh1, acc[mt][1], 0, 0, 0);
            acc[mt][1] = __builtin_amdgcn_mfma_f32_16x16x32_bf16(al, bh1, acc[mt][1], 0, 0, 0);
            acc[mt][1] = __builtin_amdgcn_mfma_f32_16x16x32_bf16(ah, bl1, acc[mt][1], 0, 0, 0);
        }
    }
    int col = lane & 15;
#pragma unroll
    for (int mt = 0; mt < 4; ++mt) {
        float* cp = c1 + (size_t)(m0 + mt * 16 + quad * 4) * TD3 + n0 + col;
#pragma unroll
        for (int r = 0; r < 4; ++r) {
            cp[(size_t)r * TD3]      = acc[mt][0][r];
            cp[(size_t)r * TD3 + 16] = acc[mt][1][r];
        }
    }
}

// K3: attn dot (q.k)/8 * sigmoid(filter) -> FHN  (validated, unchanged)
__global__ __launch_bounds__(256) void k3_fhn(const float* __restrict__ c1,
                                              const float* __restrict__ sfilt,
                                              float* __restrict__ fhn) {
    int idx = blockIdx.x * 256 + threadIdx.x;
    if (idx >= Bc * Hc * Kc) return;
    int kk = idx & 31;
    int bh = idx >> 5;
    int h  = bh % Hc;
    int r  = (bh / Hc) * Kc + kk;

    const float* qp = c1 + (size_t)r * TD3 + h * HDc;
    const float* kp = qp + Dc;
    float s = 0.f;
#pragma unroll
    for (int dd = 0; dd < HDc; ++dd) s = fmaf(qp[dd], kp[dd], s);
    s *= 0.125f;

    float filt = 1.f / (1.f + __expf(-sfilt[h * 32 + kk]));
    s *= filt;

    float as    = fabsf(s);
    float scale = fmaxf(as, 1e-6f);
    float sn    = s / scale;
    float gate  = 1.f / (1.f + __expf(-(as - 0.5f) * 10.f));
    float I     = sn * (0.1f + 0.9f * gate);
    const float alpha = 0.08f;
    const float denom = 1.064f;
    float v = 0.f, w = 0.f;
#pragma unroll
    for (int it = 0; it < 2; ++it) {
        float dv = v - (v * v * v) / 3.f - w + I;
        float vn = v + dv;
        float wn = (w + (vn + 0.7f) * alpha) / denom;
        v = fminf(fmaxf(vn, -3.f), 3.f);
        w = fminf(fmaxf(wn, -3.f), 3.f);
    }
    fhn[idx] = v * scale;
}

// K4: proj[r,e] = sum_c (fhn * v_spec[r,c]) * wout[e,c]  (validated, unchanged)
__global__ __launch_bounds__(256) void k4_proj(const float* __restrict__ c1,
                                               const float* __restrict__ fhn,
                                               const float* __restrict__ wout,
                                               float* __restrict__ proj) {
    int wave = blockIdx.x * 4 + (threadIdx.x >> 6);   // 48 blocks -> 192 waves
    int lane = threadIdx.x & 63;
    int mb = wave & 3;
    int nt = wave >> 2;
    int m0 = mb * 64, n0 = nt * 16;
    int m = lane & 15, quad = lane >> 4;

    const float* bp = wout + (size_t)(n0 + m) * Dc + quad * 8;

    float4v acc[4];
#pragma unroll
    for (int i = 0; i < 4; ++i) acc[i] = (float4v){0.f, 0.f, 0.f, 0.f};

    for (int s = 0; s < 24; ++s) {
        short8 bh, bl;
        split8(bp + s * 32, bh, bl);
        int c0 = s * 32 + quad * 8;
        int h  = c0 >> 6;
#pragma unroll
        for (int mt = 0; mt < 4; ++mt) {
            int r = m0 + mt * 16 + m;
            int b = r >> 5, kk = r & 31;
            float f = fhn[(size_t)b * Hc * Kc + h * Kc + kk];
            const float* apx = c1 + (size_t)r * TD3 + 2 * Dc + s * 32 + quad * 8;
            float av[8];
#pragma unroll
            for (int i = 0; i < 8; ++i) av[i] = apx[i] * f;
            short8 ah, al;
            split8(av, ah, al);
            acc[mt] = __builtin_amdgcn_mfma_f32_16x16x32_bf16(ah, bh, acc[mt], 0, 0, 0);
            acc[mt] = __builtin_amdgcn_mfma_f32_16x16x32_bf16(al, bh, acc[mt], 0, 0, 0);
            acc[mt] = __builtin_amdgcn_mfma_f32_16x16x32_bf16(ah, bl, acc[mt], 0, 0, 0);
        }
    }
#pragma unroll
    for (int mt = 0; mt < 4; ++mt) {
        float* cp = proj + (size_t)(m0 + mt * 16 + quad * 4) * Dc + n0 + (lane & 15);
#pragma unroll
        for (int r = 0; r < 4; ++r) cp[(size_t)r * Dc] = acc[mt][r];
    }
}

// ---------------------------------------------------------------------------
// K5: out[b,t,e] = sum_k sb[b,t,k] * proj[b,k,e]
// MFMA GEMM: M=t, N=e, K=32 (single k-step).
// Grid 1024 = 8b x 64tt(64 t) x 2et(384 e); block 256 thr = 4 waves (16 t each).
// A = sb rows: contiguous float4 loads. B = proj: L2-resident dword gathers.
// ---------------------------------------------------------------------------
__global__ __launch_bounds__(256) void k5_out(const float* __restrict__ proj,
                                              const float* __restrict__ sb,
                                              float* __restrict__ out) {
    int tid  = threadIdx.x;
    int w    = tid >> 6;
    int lane = tid & 63;
    int col  = lane & 15;
    int quad = lane >> 4;

    int bid = blockIdx.x;
    int b  = bid >> 7;
    int tt = (bid >> 1) & 63;
    int et = bid & 1;
    int t0 = tt * 64 + w * 16;
    int e0 = et * 384;

    // A fragment: sb[t0+col, 0..32), k = quad*8+j  (contiguous per lane)
    const float* apx = sb + ((size_t)b * Tc + t0 + col) * Kc + quad * 8;
    short8 ah, al;
    split8(apx, ah, al);

    const float* pp = proj + (size_t)b * Kc * Dc;

    float4v acc[24];
#pragma unroll
    for (int ni = 0; ni < 24; ++ni) acc[ni] = (float4v){0.f, 0.f, 0.f, 0.f};

#pragma unroll
    for (int ni = 0; ni < 24; ++ni) {
        float bv[8];
#pragma unroll
        for (int j = 0; j < 8; ++j)
            bv[j] = pp[(size_t)(quad * 8 + j) * Dc + e0 + ni * 16 + col];
        short8 bh, bl;
        split8(bv, bh, bl);
        acc[ni] = __builtin_amdgcn_mfma_f32_16x16x32_bf16(ah, bh, acc[ni], 0, 0, 0);
        acc[ni] = __builtin_amdgcn_mfma_f32_16x16x32_bf16(al, bh, acc[ni], 0, 0, 0);
        acc[ni] = __builtin_amdgcn_mfma_f32_16x16x32_bf16(ah, bl, acc[ni], 0, 0, 0);
    }

    float* op = out + ((size_t)b * Tc + t0 + quad * 4) * Dc + e0 + col;
#pragma unroll
    for (int ni = 0; ni < 24; ++ni)
#pragma unroll
        for (int r = 0; r < 4; ++r)
            op[(size_t)r * Dc + ni * 16] = acc[ni][r];
}

extern "C" void kernel_launch(void* const* d_in, const int* in_sizes, int n_in,
                              void* d_out, int out_size, void* d_ws, size_t ws_size,
                              hipStream_t stream) {
    const float* x     = (const float*)d_in[0];
    const float* sb    = (const float*)d_in[1];
    const float* wqkv  = (const float*)d_in[2];
    const float* wout  = (const float*)d_in[3];
    const float* sfilt = (const float*)d_in[4];
    float* out = (float*)d_out;

    float* pb   = (float*)d_ws;                      // [8][B*K*D]  1572864 f (6 MB)
    float* xs   = pb + (size_t)8 * Bc * Kc * Dc;     // [B][K][D]    196608 f
    float* c1   = xs + (size_t)Bc * Kc * Dc;         // [256][2304]  589824 f
    float* fhn  = c1 + (size_t)Bc * Kc * TD3;        // [B][H][K]      3072 f
    float* proj = fhn + (size_t)Bc * Hc * Kc;        // [256][768]   196608 f

    hipLaunchKernelGGL(k1_xspec,   dim3(256),  dim3(512), 0, stream, x, sb, pb);
    hipLaunchKernelGGL(k1r_reduce, dim3(192),  dim3(256), 0, stream, pb, xs);
    hipLaunchKernelGGL(k2_qkv,     dim3(72),   dim3(256), 0, stream, xs, wqkv, c1);
    hipLaunchKernelGGL(k3_fhn,     dim3(12),   dim3(256), 0, stream, c1, sfilt, fhn);
    hipLaunchKernelGGL(k4_proj,    dim3(48),   dim3(256), 0, stream, c1, fhn, wout, proj);
    hipLaunchKernelGGL(k5_out,     dim3(1024), dim3(256), 0, stream, proj, sb, out);
}

// Round 5
// 339.872 us; speedup vs baseline: 1.5080x; 1.1931x over previous
//
#include <hip/hip_runtime.h>

#define Bc 8
#define Tc 4096
#define Dc 768
#define Hc 12
#define HDc 64
#define Kc 32
#define TD3 2304

typedef __attribute__((ext_vector_type(8))) short short8;
typedef __attribute__((ext_vector_type(4))) float float4v;

__device__ __forceinline__ float bf2f(unsigned short u) {
    unsigned v = ((unsigned)u) << 16;
    return __builtin_bit_cast(float, v);
}
__device__ __forceinline__ unsigned short f2bf(float f) {
    unsigned u = __builtin_bit_cast(unsigned, f);
    u += 0x7FFFu + ((u >> 16) & 1u);   // RNE
    return (unsigned short)(u >> 16);
}

// split 8 fp32 into bf16 hi + bf16 lo fragments (hi+lo ~ fp32 precision)
__device__ __forceinline__ void split8(const float* p, short8& hi, short8& lo) {
#pragma unroll
    for (int i = 0; i < 8; ++i) {
        unsigned short h = f2bf(p[i]);
        hi[i] = (short)h;
        lo[i] = (short)f2bf(p[i] - bf2f(h));
    }
}

// ---------------------------------------------------------------------------
// K1: pb[tc][b][kk][d] = sum_{t in 256-chunk tc} sb[b,t,kk] * x[b,t,d]
// LDS-staged MFMA GEMM: M=32(kk), N=192(d)/block, K=256(t)/block in 8 sub-tiles.
// Fragments (verified idiom): A[m=lane&15][k=quad*8+j], B[n=lane&15][k=quad*8+j],
// C: row=quad*4+r, col=lane&15.
// Waves split N (3 of 12 n-subtiles each); acc lives in registers across K.
// Exclusive pb region per (tc,b,dt,wave) -> no atomics.
// ---------------------------------------------------------------------------
__global__ __launch_bounds__(256) void k1_xspec(const float* __restrict__ x,
                                                const float* __restrict__ sb,
                                                float* __restrict__ pb) {
    __shared__ float xt[32 * 193];   // x tile,  stride 193 -> <=2-way conflicts
    __shared__ float st[32 * 33];    // sb tile, stride 33  -> <=2-way conflicts

    int tid  = threadIdx.x;
    int w    = tid >> 6;
    int lane = tid & 63;
    int col  = lane & 15;
    int quad = lane >> 4;

    int bid = blockIdx.x;            // 512 = 8b x 4dt x 16tc
    int b  = bid >> 6;
    int dt = (bid >> 4) & 3;
    int tc = bid & 15;
    int d0 = dt * 192;
    size_t bT = (size_t)b * Tc + (size_t)tc * 256;

    float4v acc[2][3];
#pragma unroll
    for (int mi = 0; mi < 2; ++mi)
#pragma unroll
        for (int ni = 0; ni < 3; ++ni) acc[mi][ni] = (float4v){0.f, 0.f, 0.f, 0.f};

    for (int ks = 0; ks < 8; ++ks) {
        __syncthreads();   // previous sub-tile's reads complete
        // stage x[32t x 192d]: 1536 float4, 6 per thread, coalesced
#pragma unroll
        for (int i = 0; i < 6; ++i) {
            int f4  = tid + i * 256;
            int row = f4 / 48, c4 = f4 % 48;
            float4v v = *(const float4v*)&x[(bT + ks * 32 + row) * Dc + d0 + c4 * 4];
#pragma unroll
            for (int q = 0; q < 4; ++q) xt[row * 193 + c4 * 4 + q] = v[q];
        }
        // stage sb[32t x 32k]: 256 float4, 1 per thread, coalesced
        {
            int row = tid >> 3, c4 = tid & 7;
            float4v v = *(const float4v*)&sb[(bT + ks * 32 + row) * Kc + c4 * 4];
#pragma unroll
            for (int q = 0; q < 4; ++q) st[row * 33 + c4 * 4 + q] = v[q];
        }
        __syncthreads();

        // A fragments (sb)
        short8 ah[2], al[2];
#pragma unroll
        for (int mi = 0; mi < 2; ++mi) {
            float av[8];
#pragma unroll
            for (int j = 0; j < 8; ++j)
                av[j] = st[(quad * 8 + j) * 33 + mi * 16 + col];
            split8(av, ah[mi], al[mi]);
        }
        // B fragments (x) + MFMA
#pragma unroll
        for (int ni = 0; ni < 3; ++ni) {
            int nc = (w * 3 + ni) * 16 + col;
            float bv[8];
#pragma unroll
            for (int j = 0; j < 8; ++j)
                bv[j] = xt[(quad * 8 + j) * 193 + nc];
            short8 bh, bl;
            split8(bv, bh, bl);
#pragma unroll
            for (int mi = 0; mi < 2; ++mi) {
                acc[mi][ni] = __builtin_amdgcn_mfma_f32_16x16x32_bf16(ah[mi], bh, acc[mi][ni], 0, 0, 0);
                acc[mi][ni] = __builtin_amdgcn_mfma_f32_16x16x32_bf16(al[mi], bh, acc[mi][ni], 0, 0, 0);
                acc[mi][ni] = __builtin_amdgcn_mfma_f32_16x16x32_bf16(ah[mi], bl, acc[mi][ni], 0, 0, 0);
            }
        }
    }

    // exclusive write to pb[tc]
    float* pbp = pb + (size_t)tc * (Bc * Kc * Dc);
#pragma unroll
    for (int mi = 0; mi < 2; ++mi)
#pragma unroll
        for (int ni = 0; ni < 3; ++ni)
#pragma unroll
            for (int r = 0; r < 4; ++r) {
                int kk = mi * 16 + quad * 4 + r;
                int dd = d0 + (w * 3 + ni) * 16 + col;
                pbp[((size_t)(b * Kc + kk)) * Dc + dd] = acc[mi][ni][r];
            }
}

// reduce 16 partials -> xs
__global__ __launch_bounds__(256) void k1r_reduce(const float* __restrict__ pb,
                                                  float* __restrict__ xs) {
    int i = (blockIdx.x * 256 + threadIdx.x) * 4;   // 192 blocks -> 196608 floats
    float4v s = (float4v){0.f, 0.f, 0.f, 0.f};
#pragma unroll
    for (int p = 0; p < 16; ++p) {
        float4v v = *(const float4v*)(pb + (size_t)p * (Bc * Kc * Dc) + i);
#pragma unroll
        for (int q = 0; q < 4; ++q) s[q] += v[q];
    }
    *(float4v*)(xs + i) = s;
}

// K2: c1[r, j] = sum_c xs[r, c] * wqkv[j, c]  (validated, unchanged)
__global__ __launch_bounds__(256) void k2_qkv(const float* __restrict__ xs,
                                              const float* __restrict__ wqkv,
                                              float* __restrict__ c1) {
    int wave = blockIdx.x * 4 + (threadIdx.x >> 6);   // 72 blocks -> 288 waves
    int lane = threadIdx.x & 63;
    int mb = wave & 3;
    int nt = wave >> 2;
    int m0 = mb * 64, n0 = nt * 32;
    int m = lane & 15, quad = lane >> 4;

    const float* ap  = xs   + (size_t)(m0 + m) * Dc + quad * 8;
    const float* bp0 = wqkv + (size_t)(n0 + m) * Dc + quad * 8;
    const float* bp1 = bp0 + (size_t)16 * Dc;

    float4v acc[4][2];
#pragma unroll
    for (int i = 0; i < 4; ++i)
#pragma unroll
        for (int j = 0; j < 2; ++j) acc[i][j] = (float4v){0.f, 0.f, 0.f, 0.f};

    for (int s = 0; s < 24; ++s) {
        short8 bh0, bl0, bh1, bl1;
        split8(bp0 + s * 32, bh0, bl0);
        split8(bp1 + s * 32, bh1, bl1);
#pragma unroll
        for (int mt = 0; mt < 4; ++mt) {
            short8 ah, al;
            split8(ap + (size_t)mt * 16 * Dc + s * 32, ah, al);
            acc[mt][0] = __builtin_amdgcn_mfma_f32_16x16x32_bf16(ah, bh0, acc[mt][0], 0, 0, 0);
            acc[mt][0] = __builtin_amdgcn_mfma_f32_16x16x32_bf16(al, bh0, acc[mt][0], 0, 0, 0);
            acc[mt][0] = __builtin_amdgcn_mfma_f32_16x16x32_bf16(ah, bl0, acc[mt][0], 0, 0, 0);
            acc[mt][1] = __builtin_amdgcn_mfma_f32_16x16x32_bf16(ah, bh1, acc[mt][1], 0, 0, 0);
            acc[mt][1] = __builtin_amdgcn_mfma_f32_16x16x32_bf16(al, bh1, acc[mt][1], 0, 0, 0);
            acc[mt][1] = __builtin_amdgcn_mfma_f32_16x16x32_bf16(ah, bl1, acc[mt][1], 0, 0, 0);
        }
    }
    int col = lane & 15;
#pragma unroll
    for (int mt = 0; mt < 4; ++mt) {
        float* cp = c1 + (size_t)(m0 + mt * 16 + quad * 4) * TD3 + n0 + col;
#pragma unroll
        for (int r = 0; r < 4; ++r) {
            cp[(size_t)r * TD3]      = acc[mt][0][r];
            cp[(size_t)r * TD3 + 16] = acc[mt][1][r];
        }
    }
}

// K3: attn dot (q.k)/8 * sigmoid(filter) -> FHN  (validated, unchanged)
__global__ __launch_bounds__(256) void k3_fhn(const float* __restrict__ c1,
                                              const float* __restrict__ sfilt,
                                              float* __restrict__ fhn) {
    int idx = blockIdx.x * 256 + threadIdx.x;
    if (idx >= Bc * Hc * Kc) return;
    int kk = idx & 31;
    int bh = idx >> 5;
    int h  = bh % Hc;
    int r  = (bh / Hc) * Kc + kk;

    const float* qp = c1 + (size_t)r * TD3 + h * HDc;
    const float* kp = qp + Dc;
    float s = 0.f;
#pragma unroll
    for (int dd = 0; dd < HDc; ++dd) s = fmaf(qp[dd], kp[dd], s);
    s *= 0.125f;

    float filt = 1.f / (1.f + __expf(-sfilt[h * 32 + kk]));
    s *= filt;

    float as    = fabsf(s);
    float scale = fmaxf(as, 1e-6f);
    float sn    = s / scale;
    float gate  = 1.f / (1.f + __expf(-(as - 0.5f) * 10.f));
    float I     = sn * (0.1f + 0.9f * gate);
    const float alpha = 0.08f;
    const float denom = 1.064f;
    float v = 0.f, w = 0.f;
#pragma unroll
    for (int it = 0; it < 2; ++it) {
        float dv = v - (v * v * v) / 3.f - w + I;
        float vn = v + dv;
        float wn = (w + (vn + 0.7f) * alpha) / denom;
        v = fminf(fmaxf(vn, -3.f), 3.f);
        w = fminf(fmaxf(wn, -3.f), 3.f);
    }
    fhn[idx] = v * scale;
}

// K4: proj[r,e] = sum_c (fhn * v_spec[r,c]) * wout[e,c]  (validated, unchanged)
__global__ __launch_bounds__(256) void k4_proj(const float* __restrict__ c1,
                                               const float* __restrict__ fhn,
                                               const float* __restrict__ wout,
                                               float* __restrict__ proj) {
    int wave = blockIdx.x * 4 + (threadIdx.x >> 6);   // 48 blocks -> 192 waves
    int lane = threadIdx.x & 63;
    int mb = wave & 3;
    int nt = wave >> 2;
    int m0 = mb * 64, n0 = nt * 16;
    int m = lane & 15, quad = lane >> 4;

    const float* bp = wout + (size_t)(n0 + m) * Dc + quad * 8;

    float4v acc[4];
#pragma unroll
    for (int i = 0; i < 4; ++i) acc[i] = (float4v){0.f, 0.f, 0.f, 0.f};

    for (int s = 0; s < 24; ++s) {
        short8 bh, bl;
        split8(bp + s * 32, bh, bl);
        int c0 = s * 32 + quad * 8;
        int h  = c0 >> 6;
#pragma unroll
        for (int mt = 0; mt < 4; ++mt) {
            int r = m0 + mt * 16 + m;
            int b = r >> 5, kk = r & 31;
            float f = fhn[(size_t)b * Hc * Kc + h * Kc + kk];
            const float* apx = c1 + (size_t)r * TD3 + 2 * Dc + s * 32 + quad * 8;
            float av[8];
#pragma unroll
            for (int i = 0; i < 8; ++i) av[i] = apx[i] * f;
            short8 ah, al;
            split8(av, ah, al);
            acc[mt] = __builtin_amdgcn_mfma_f32_16x16x32_bf16(ah, bh, acc[mt], 0, 0, 0);
            acc[mt] = __builtin_amdgcn_mfma_f32_16x16x32_bf16(al, bh, acc[mt], 0, 0, 0);
            acc[mt] = __builtin_amdgcn_mfma_f32_16x16x32_bf16(ah, bl, acc[mt], 0, 0, 0);
        }
    }
#pragma unroll
    for (int mt = 0; mt < 4; ++mt) {
        float* cp = proj + (size_t)(m0 + mt * 16 + quad * 4) * Dc + n0 + (lane & 15);
#pragma unroll
        for (int r = 0; r < 4; ++r) cp[(size_t)r * Dc] = acc[mt][r];
    }
}

// ---------------------------------------------------------------------------
// K5: out[b,t,e] = sum_k sb[b,t,k] * proj[b,k,e]
// MFMA GEMM M=t, N=e, K=32 (one k-step). proj tile staged in LDS (L2-resident
// source); sb A-fragments are per-lane contiguous 32B global loads.
// Grid 2048 = 8b x 64tt(64 t) x 4et(192 e); block = 4 waves x 16 t.
// ---------------------------------------------------------------------------
__global__ __launch_bounds__(256) void k5_out(const float* __restrict__ proj,
                                              const float* __restrict__ sb,
                                              float* __restrict__ out) {
    __shared__ float pt[32 * 193];

    int tid  = threadIdx.x;
    int w    = tid >> 6;
    int lane = tid & 63;
    int col  = lane & 15;
    int quad = lane >> 4;

    int bid = blockIdx.x;
    int b  = bid >> 8;
    int tt = (bid >> 2) & 63;
    int et = bid & 3;
    int t0 = tt * 64 + w * 16;
    int e0 = et * 192;

    // stage proj[b][0..32)[e0..e0+192): 1536 float4, 6 per thread, coalesced
#pragma unroll
    for (int i = 0; i < 6; ++i) {
        int f4  = tid + i * 256;
        int row = f4 / 48, c4 = f4 % 48;
        float4v v = *(const float4v*)&proj[(size_t)b * Kc * Dc + (size_t)row * Dc + e0 + c4 * 4];
#pragma unroll
        for (int q = 0; q < 4; ++q) pt[row * 193 + c4 * 4 + q] = v[q];
    }

    // A fragment: sb[t0+col][quad*8 .. +8): contiguous per lane
    const float* apx = sb + ((size_t)b * Tc + t0 + col) * Kc + quad * 8;
    short8 ah, al;
    split8(apx, ah, al);

    __syncthreads();

    float4v acc[12];
#pragma unroll
    for (int ni = 0; ni < 12; ++ni) acc[ni] = (float4v){0.f, 0.f, 0.f, 0.f};

#pragma unroll
    for (int ni = 0; ni < 12; ++ni) {
        float bv[8];
#pragma unroll
        for (int j = 0; j < 8; ++j)
            bv[j] = pt[(quad * 8 + j) * 193 + ni * 16 + col];
        short8 bh, bl;
        split8(bv, bh, bl);
        acc[ni] = __builtin_amdgcn_mfma_f32_16x16x32_bf16(ah, bh, acc[ni], 0, 0, 0);
        acc[ni] = __builtin_amdgcn_mfma_f32_16x16x32_bf16(al, bh, acc[ni], 0, 0, 0);
        acc[ni] = __builtin_amdgcn_mfma_f32_16x16x32_bf16(ah, bl, acc[ni], 0, 0, 0);
    }

    float* op = out + ((size_t)b * Tc + t0 + quad * 4) * Dc + e0 + col;
#pragma unroll
    for (int ni = 0; ni < 12; ++ni)
#pragma unroll
        for (int r = 0; r < 4; ++r)
            op[(size_t)r * Dc + ni * 16] = acc[ni][r];
}

extern "C" void kernel_launch(void* const* d_in, const int* in_sizes, int n_in,
                              void* d_out, int out_size, void* d_ws, size_t ws_size,
                              hipStream_t stream) {
    const float* x     = (const float*)d_in[0];
    const float* sb    = (const float*)d_in[1];
    const float* wqkv  = (const float*)d_in[2];
    const float* wout  = (const float*)d_in[3];
    const float* sfilt = (const float*)d_in[4];
    float* out = (float*)d_out;

    float* pb   = (float*)d_ws;                      // [16][B*K*D] 3145728 f (12.6 MB)
    float* xs   = pb + (size_t)16 * Bc * Kc * Dc;    // [B][K][D]    196608 f
    float* c1   = xs + (size_t)Bc * Kc * Dc;         // [256][2304]  589824 f
    float* fhn  = c1 + (size_t)Bc * Kc * TD3;        // [B][H][K]      3072 f
    float* proj = fhn + (size_t)Bc * Hc * Kc;        // [256][768]   196608 f

    hipLaunchKernelGGL(k1_xspec,   dim3(512),  dim3(256), 0, stream, x, sb, pb);
    hipLaunchKernelGGL(k1r_reduce, dim3(192),  dim3(256), 0, stream, pb, xs);
    hipLaunchKernelGGL(k2_qkv,     dim3(72),   dim3(256), 0, stream, xs, wqkv, c1);
    hipLaunchKernelGGL(k3_fhn,     dim3(12),   dim3(256), 0, stream, c1, sfilt, fhn);
    hipLaunchKernelGGL(k4_proj,    dim3(48),   dim3(256), 0, stream, c1, fhn, wout, proj);
    hipLaunchKernelGGL(k5_out,     dim3(2048), dim3(256), 0, stream, proj, sb, out);
}